// Round 10
// baseline (270.846 us; speedup 1.0000x reference)
//
#include <hip/hip_runtime.h>
#include <hip/hip_bf16.h>

typedef unsigned short ushort_t;
typedef __attribute__((ext_vector_type(8))) short short8;
typedef __attribute__((ext_vector_type(4))) float floatx4;

#define LOG2E 1.4426950408889634f

__device__ __forceinline__ unsigned short f2bf(float f) {
    unsigned u = __float_as_uint(f);
    u += 0x7FFF + ((u >> 16) & 1);   // RNE
    return (unsigned short)(u >> 16);
}

__device__ __forceinline__ void async_ld16(const void* gptr, void* lptr) {
    typedef const __attribute__((address_space(1))) unsigned int TG;
    typedef __attribute__((address_space(3))) unsigned int TL;
    __builtin_amdgcn_global_load_lds((TG*)(unsigned long long)gptr,
                                     (TL*)(unsigned)(unsigned long long)lptr,
                                     16, 0, 0);
}

// ---------------- fused prep: x->bf16 | w_qkv transpose | w_proj transpose ----------------
__global__ __launch_bounds__(256) void prep_kernel(const float* __restrict__ x,
                                                   const float* __restrict__ wqkv,
                                                   const float* __restrict__ wproj,
                                                   ushort_t* __restrict__ xb,
                                                   ushort_t* __restrict__ wqkvT,
                                                   ushort_t* __restrict__ wprojT) {
    __shared__ float t[32][33];
    int bx = blockIdx.x;
    if (bx < 8192) {
        int i = bx * 256 + threadIdx.x;
        float4 v = ((const float4*)x)[i];
        unsigned long long r = (unsigned long long)f2bf(v.x)
                             | ((unsigned long long)f2bf(v.y) << 16)
                             | ((unsigned long long)f2bf(v.z) << 32)
                             | ((unsigned long long)f2bf(v.w) << 48);
        ((unsigned long long*)xb)[i] = r;
        return;
    }
    const float* in; ushort_t* out; int R, C, bidx;
    if (bx < 8192 + 3072) { in = wqkv; out = wqkvT; R = 1024; C = 3072; bidx = bx - 8192; }
    else                  { in = wproj; out = wprojT; R = 1024; C = 1024; bidx = bx - 11264; }
    int nbc = C >> 5;
    int bc = bidx % nbc, br = bidx / nbc;
    int tx = threadIdx.x & 31, ty = threadIdx.x >> 5;   // 32 x 8
    int r0 = br << 5, c0 = bc << 5;
#pragma unroll
    for (int j = 0; j < 4; ++j)
        t[ty + j * 8][tx] = in[(size_t)(r0 + ty + j * 8) * C + c0 + tx];
    __syncthreads();
#pragma unroll
    for (int j = 0; j < 4; ++j)
        out[(size_t)(c0 + ty + j * 8) * R + r0 + tx] = f2bf(t[tx][ty + j * 8]);
}

// ---------------- QKV GEMM: [8192,1024]@[1024,3072]^T + bias -> split Q/K/Vt ----------------
// Q,K: [bh][s][64] bf16 ; Vt: [bh][64][2048] bf16; Q pre-scaled by 0.125*log2e.
// Coalesced epilogue staged through LDS in TWO passes (one head at a time) so
// the staging buffer is 17.4 KB, not 36.9 KB — R9's 36.9 KB halved K-loop
// residency (2.3 blocks/CU) and ate the epilogue win.
__global__ __launch_bounds__(256) void gemm_qkv_kernel(const ushort_t* __restrict__ A,
                                                       const ushort_t* __restrict__ Bt,
                                                       const float* __restrict__ bias,
                                                       ushort_t* __restrict__ qbuf,
                                                       ushort_t* __restrict__ kbuf,
                                                       ushort_t* __restrict__ vtbuf) {
    const int K = 1024, nbn = 24;
    __shared__ __align__(16) ushort_t smem[8704];    // 17.4 KB; K-loop uses first 16 KB
    ushort_t* As = smem;          // 4096
    ushort_t* Bs = smem + 4096;   // 4096
    int bm = blockIdx.x / nbn, bn = blockIdx.x % nbn;
    int m0 = bm << 7, n0 = bn << 7;
    int tid = threadIdx.x;
    int wave = tid >> 6, lane = tid & 63;
    int c = lane & 15, g = lane >> 4;
    int m_off = (wave & 1) << 6, n_off = (wave >> 1) << 6;
    int ldrow = lane >> 2;
    int ldk   = (lane & 3) << 3;

    floatx4 acc[4][4];
#pragma unroll
    for (int mi = 0; mi < 4; ++mi)
#pragma unroll
        for (int ni = 0; ni < 4; ++ni) {
            floatx4 z = {0.f, 0.f, 0.f, 0.f};
            acc[mi][ni] = z;
        }

    for (int kk = 0; kk < K; kk += 32) {
        __syncthreads();
#pragma unroll
        for (int j = 0; j < 2; ++j) {
            int chunk = wave * 2 + j;
            async_ld16(A  + (size_t)(m0 + chunk * 16 + ldrow) * K + kk + ldk, &As[chunk * 512]);
            async_ld16(Bt + (size_t)(n0 + chunk * 16 + ldrow) * K + kk + ldk, &Bs[chunk * 512]);
        }
        __syncthreads();
        short8 bf[4];
#pragma unroll
        for (int ni = 0; ni < 4; ++ni)
            bf[ni] = *(const short8*)&Bs[(n_off + ni * 16 + c) * 32 + g * 8];
#pragma unroll
        for (int mi = 0; mi < 4; ++mi) {
            short8 af = *(const short8*)&As[(m_off + mi * 16 + c) * 32 + g * 8];
#pragma unroll
            for (int ni = 0; ni < 4; ++ni)
                acc[mi][ni] = __builtin_amdgcn_mfma_f32_16x16x32_bf16(af, bf[ni], acc[mi][ni], 0, 0, 0);
        }
    }

    int sec = n0 >> 10;               // 0=Q 1=K 2=V (block-uniform)
    int h0 = (n0 & 1023) >> 6;        // first head in this 128-col tile
    int b  = m0 >> 11, sbase = m0 & 2047;
    int bh0 = b * 16 + h0;
    float bv[4];
#pragma unroll
    for (int ni = 0; ni < 4; ++ni) bv[ni] = bias[n0 + n_off + ni * 16 + c];
    int hl = wave >> 1;               // this wave's local head (0 or 1)
    float scl = (sec == 0) ? (0.125f * LOG2E) : 1.0f;

#pragma unroll
    for (int p = 0; p < 2; ++p) {
        __syncthreads();              // p=0: waves done reading As/Bs; p=1: copies done
        if (sec < 2) {
            if (hl == p) {
                // stage [row 128][col 64], row stride 68 (16B-aligned)
#pragma unroll
                for (int mi = 0; mi < 4; ++mi)
#pragma unroll
                    for (int ni = 0; ni < 4; ++ni) {
                        int colb = ni * 16 + c;
#pragma unroll
                        for (int r = 0; r < 4; ++r) {
                            int row = m_off + mi * 16 + g * 4 + r;
                            smem[row * 68 + colb] = f2bf((acc[mi][ni][r] + bv[ni]) * scl);
                        }
                    }
            }
            __syncthreads();
            // copy head h0+p: thread -> half a q-row (32 cols = 64 B)
            ushort_t* dstbase = (sec == 0 ? qbuf : kbuf);
            int row = tid >> 1, half = tid & 1;
            const ushort_t* src = &smem[row * 68 + half * 32];
            ushort_t* dst = dstbase + (size_t)(bh0 + p) * 131072
                          + (size_t)(sbase + row) * 64 + half * 32;
#pragma unroll
            for (int j = 0; j < 4; ++j)
                *(short8*)(dst + j * 8) = *(const short8*)(src + j * 8);
        } else {
            if (hl == p) {
                // stage [d 64][s 128], d stride 132 (16B-aligned); packed b64 along s
#pragma unroll
                for (int mi = 0; mi < 4; ++mi)
#pragma unroll
                    for (int ni = 0; ni < 4; ++ni) {
                        int d = ni * 16 + c;
                        int rowb = m_off + mi * 16 + g * 4;
                        unsigned long long pk = 0;
#pragma unroll
                        for (int r = 0; r < 4; ++r)
                            pk |= (unsigned long long)f2bf(acc[mi][ni][r] + bv[ni]) << (16 * r);
                        *(unsigned long long*)&smem[d * 132 + rowb] = pk;
                    }
            }
            __syncthreads();
            // copy head h0+p: thread -> quarter d-row (32 s = 64 B)
            int d = tid >> 2, q = tid & 3;
            const ushort_t* src = &smem[d * 132 + q * 32];
            ushort_t* dst = vtbuf + (size_t)(bh0 + p) * 131072
                          + (size_t)d * 2048 + sbase + q * 32;
#pragma unroll
            for (int j = 0; j < 4; ++j)
                *(short8*)(dst + j * 8) = *(const short8*)(src + j * 8);
        }
    }
}

// ---------------- flash attention: 1 block = (b,h) x 64 q-rows, 64-kp tiles ----------------
// Single strip per wave; 26.1 KB LDS; (256,5) -> 5 blocks/CU spill-free.
// Conflict-free stride-68 LDS, transposed softmax, no online max, LPT
// dispatch, post-barrier register prefetch.
__global__ __launch_bounds__(256, 5) void attn_kernel(const ushort_t* __restrict__ qb_,
                                                      const ushort_t* __restrict__ kb_,
                                                      const ushort_t* __restrict__ vtb_,
                                                      ushort_t* __restrict__ aout) {
    __shared__ __align__(16) ushort_t Ks[64 * 68];       // [kp][d] stride 68
    __shared__ __align__(16) ushort_t Vs[64 * 68];       // [d][kp] stride 68
    __shared__ __align__(16) ushort_t Ps[4][16 * 68];    // per-wave P[q][kp]
    int bx = blockIdx.x;
    int qb = 31 - (bx >> 6);          // LPT: longest blocks dispatch first
    int bhix = bx & 63;
    int b = bhix >> 4, h = bhix & 15;
    int q0 = qb << 6;
    int tid = threadIdx.x, wave = tid >> 6, lane = tid & 63;
    int c = lane & 15, g = lane >> 4;
    size_t bh = (size_t)(b * 16 + h);

    const ushort_t* Qp = qb_ + (bh * 2048 + q0) * 64;
    const ushort_t* Kp = kb_ + bh * 131072;
    const ushort_t* Vp = vtb_ + bh * 131072;

    int qr = wave * 16 + c;
    short8 qf0 = *(const short8*)(Qp + qr * 64 + g * 8);
    short8 qf1 = *(const short8*)(Qp + qr * 64 + 32 + g * 8);

    float l_part = 0.f;
    floatx4 o_acc[4];
#pragma unroll
    for (int nt = 0; nt < 4; ++nt) { floatx4 z = {0.f,0.f,0.f,0.f}; o_acc[nt] = z; }

    short8 kreg[2], vreg[2];
#pragma unroll
    for (int it = 0; it < 2; ++it) {
        int idx = it * 256 + tid;
        kreg[it] = *(const short8*)(Kp + idx * 8);
        vreg[it] = *(const short8*)(Vp + (idx >> 3) * 2048 + (idx & 7) * 8);
    }

    int qg = q0 + wave * 16 + c;
    for (int kt = 0; kt <= qb; ++kt) {
        int kt0 = kt << 6;
        __syncthreads();
#pragma unroll
        for (int it = 0; it < 2; ++it) {
            int idx = it * 256 + tid;
            *(short8*)&Ks[(idx >> 3) * 68 + (idx & 7) * 8] = kreg[it];
            *(short8*)&Vs[(idx >> 3) * 68 + (idx & 7) * 8] = vreg[it];
        }
        __syncthreads();
        if (kt < qb) {
            int s0 = (kt + 1) << 6;
#pragma unroll
            for (int it = 0; it < 2; ++it) {
                int idx = it * 256 + tid;
                kreg[it] = *(const short8*)(Kp + s0 * 64 + idx * 8);
                vreg[it] = *(const short8*)(Vp + (idx >> 3) * 2048 + s0 + (idx & 7) * 8);
            }
        }
        bool diag = (kt == qb);

        float lp = 0.f;
#pragma unroll
        for (int nt = 0; nt < 4; ++nt) {
            short8 kf0 = *(const short8*)&Ks[(nt * 16 + c) * 68 + g * 8];
            short8 kf1 = *(const short8*)&Ks[(nt * 16 + c) * 68 + 32 + g * 8];
            floatx4 z = {0.f, 0.f, 0.f, 0.f};
            z = __builtin_amdgcn_mfma_f32_16x16x32_bf16(kf0, qf0, z, 0, 0, 0);
            z = __builtin_amdgcn_mfma_f32_16x16x32_bf16(kf1, qf1, z, 0, 0, 0);

            int kpb = kt0 + nt * 16 + g * 4;
            float p[4];
#pragma unroll
            for (int r = 0; r < 4; ++r) {
                float s = z[r];
                if (diag) s = (kpb + r > qg) ? -1e30f : s;
                p[r] = exp2f(s);
                lp += p[r];
            }
            union { unsigned long long u; __hip_bfloat162 h2[2]; } pk;
            pk.h2[0] = __float22bfloat162_rn(make_float2(p[0], p[1]));
            pk.h2[1] = __float22bfloat162_rn(make_float2(p[2], p[3]));
            *(unsigned long long*)&Ps[wave][c * 68 + nt * 16 + g * 4] = pk.u;
        }
        l_part += lp;

#pragma unroll
        for (int ks = 0; ks < 2; ++ks) {
            short8 pf = *(const short8*)&Ps[wave][c * 68 + ks * 32 + g * 8];
#pragma unroll
            for (int nt = 0; nt < 4; ++nt) {
                short8 vf = *(const short8*)&Vs[(nt * 16 + c) * 68 + ks * 32 + g * 8];
                o_acc[nt] = __builtin_amdgcn_mfma_f32_16x16x32_bf16(pf, vf, o_acc[nt], 0, 0, 0);
            }
        }
    }

    float l = l_part;
    l += __shfl_xor(l, 16);
    l += __shfl_xor(l, 32);
    float linv = 1.0f / l;
    float inv[4];
#pragma unroll
    for (int r = 0; r < 4; ++r)
        inv[r] = __shfl(linv, g * 4 + r);
#pragma unroll
    for (int nt = 0; nt < 4; ++nt)
#pragma unroll
        for (int r = 0; r < 4; ++r) {
            int q = q0 + wave * 16 + g * 4 + r;
            aout[(size_t)(b * 2048 + q) * 1024 + h * 64 + nt * 16 + c] =
                f2bf(o_acc[nt][r] * inv[r]);
        }
}

// ---------------- proj GEMM: [8192,1024]@[1024,1024]^T + bias -> fp32 ----------------
__global__ __launch_bounds__(256) void gemm_proj_kernel(const ushort_t* __restrict__ A,
                                                        const ushort_t* __restrict__ Bt,
                                                        const float* __restrict__ bias,
                                                        float* __restrict__ Cout) {
    const int K = 1024, N = 1024, nbn = 8;
    __shared__ __align__(16) ushort_t As[128 * 32];
    __shared__ __align__(16) ushort_t Bs[128 * 32];
    int bm = blockIdx.x / nbn, bn = blockIdx.x % nbn;
    int m0 = bm << 7, n0 = bn << 7;
    int tid = threadIdx.x;
    int wave = tid >> 6, lane = tid & 63;
    int c = lane & 15, g = lane >> 4;
    int m_off = (wave & 1) << 6, n_off = (wave >> 1) << 6;
    int ldrow = lane >> 2;
    int ldk   = (lane & 3) << 3;

    floatx4 acc[4][4];
#pragma unroll
    for (int mi = 0; mi < 4; ++mi)
#pragma unroll
        for (int ni = 0; ni < 4; ++ni) {
            floatx4 z = {0.f, 0.f, 0.f, 0.f};
            acc[mi][ni] = z;
        }

    for (int kk = 0; kk < K; kk += 32) {
        __syncthreads();
#pragma unroll
        for (int j = 0; j < 2; ++j) {
            int chunk = wave * 2 + j;
            async_ld16(A  + (size_t)(m0 + chunk * 16 + ldrow) * K + kk + ldk, &As[chunk * 512]);
            async_ld16(Bt + (size_t)(n0 + chunk * 16 + ldrow) * K + kk + ldk, &Bs[chunk * 512]);
        }
        __syncthreads();
        short8 bf[4];
#pragma unroll
        for (int ni = 0; ni < 4; ++ni)
            bf[ni] = *(const short8*)&Bs[(n_off + ni * 16 + c) * 32 + g * 8];
#pragma unroll
        for (int mi = 0; mi < 4; ++mi) {
            short8 af = *(const short8*)&As[(m_off + mi * 16 + c) * 32 + g * 8];
#pragma unroll
            for (int ni = 0; ni < 4; ++ni)
                acc[mi][ni] = __builtin_amdgcn_mfma_f32_16x16x32_bf16(af, bf[ni], acc[mi][ni], 0, 0, 0);
        }
    }

    float bv[4];
#pragma unroll
    for (int ni = 0; ni < 4; ++ni) bv[ni] = bias[n0 + n_off + ni * 16 + c];
#pragma unroll
    for (int mi = 0; mi < 4; ++mi)
#pragma unroll
        for (int ni = 0; ni < 4; ++ni)
#pragma unroll
            for (int r = 0; r < 4; ++r) {
                int row = m0 + m_off + mi * 16 + g * 4 + r;
                int col = n0 + n_off + ni * 16 + c;
                Cout[(size_t)row * N + col] = acc[mi][ni][r] + bv[ni];
            }
}

extern "C" void kernel_launch(void* const* d_in, const int* in_sizes, int n_in,
                              void* d_out, int out_size, void* d_ws, size_t ws_size,
                              hipStream_t stream) {
    const float* x        = (const float*)d_in[0];
    const float* c_attn_w = (const float*)d_in[1];
    const float* c_attn_b = (const float*)d_in[2];
    const float* c_proj_w = (const float*)d_in[3];
    const float* c_proj_b = (const float*)d_in[4];
    float* out = (float*)d_out;

    char* ws = (char*)d_ws;
    ushort_t* xb     = (ushort_t*)(ws);              // 16 MB; reused as attn output 'a'
    ushort_t* wqkvT  = (ushort_t*)(ws + 16777216);   // 6 MB
    ushort_t* wprojT = (ushort_t*)(ws + 23068672);   // 2 MB
    ushort_t* qbuf   = (ushort_t*)(ws + 25165824);   // 16 MB  [bh][s][64]  (pre-scaled)
    ushort_t* kbuf   = (ushort_t*)(ws + 41943040);   // 16 MB  [bh][s][64]
    ushort_t* vtbuf  = (ushort_t*)(ws + 58720256);   // 16 MB  [bh][64][2048]

    prep_kernel<<<12288, 256, 0, stream>>>(x, c_attn_w, c_proj_w, xb, wqkvT, wprojT);
    gemm_qkv_kernel<<<64 * 24, 256, 0, stream>>>(xb, wqkvT, c_attn_b, qbuf, kbuf, vtbuf);
    attn_kernel<<<2048, 256, 0, stream>>>(qbuf, kbuf, vtbuf, xb);
    gemm_proj_kernel<<<64 * 8, 256, 0, stream>>>(xb, wprojT, c_proj_b, out);
}